// Round 6
// baseline (600.719 us; speedup 1.0000x reference)
//
#include <hip/hip_runtime.h>

typedef unsigned short ushort_t;
typedef __attribute__((ext_vector_type(8))) short short8;
typedef __attribute__((ext_vector_type(4))) float f32x4;
typedef __attribute__((ext_vector_type(16))) float f32x16;
typedef __attribute__((ext_vector_type(4))) unsigned short ushort4v;

__device__ inline ushort_t f2bf(float f) {
    union { float f; unsigned u; } v; v.f = f;
    return (ushort_t)((v.u + 0x7FFFu + ((v.u >> 16) & 1u)) >> 16);
}
__device__ inline float bf2f(ushort_t u) {
    union { unsigned u; float f; } v; v.u = ((unsigned)u) << 16;
    return v.f;
}

// async global->LDS, 16B per lane. LDS dest must be wave-uniform-base + lane*16.
__device__ inline void gld16(const ushort_t* g, ushort_t* l) {
    __builtin_amdgcn_global_load_lds(
        (const __attribute__((address_space(1))) unsigned int*)g,
        (__attribute__((address_space(3))) unsigned int*)l, 16, 0, 0);
}

// XCD-aware bijective block swizzle (nwg must be a multiple of 8).
__device__ inline int xcd_swz(int id, int nwg) {
    int q = nwg >> 3;
    return (id & 7) * q + (id >> 3);
}

// ---------------------------------------------------------------------------
// Weight transpose + f32->bf16 convert:  w (K x N) f32  ->  out (N x K) bf16
// ---------------------------------------------------------------------------
__global__ void w_transpose_bf16(const float* __restrict__ w, ushort_t* __restrict__ out,
                                 int K, int N) {
    __shared__ float t[64][65];
    const int k0 = blockIdx.y * 64, n0 = blockIdx.x * 64;
    const int tid = threadIdx.x;
#pragma unroll
    for (int i = 0; i < 16; i++) {
        int idx = tid + i * 256;
        int r = idx >> 6, c = idx & 63;
        t[r][c] = w[(size_t)(k0 + r) * N + n0 + c];
    }
    __syncthreads();
#pragma unroll
    for (int i = 0; i < 16; i++) {
        int idx = tid + i * 256;
        int nr = idx >> 6, kc = idx & 63;
        out[(size_t)(n0 + nr) * K + k0 + kc] = f2bf(t[kc][nr]);
    }
}

// ---------------------------------------------------------------------------
// bf16 V (rows x D per head, strided) -> Vt [(b*16+h)*64 + d][Lk]
// ---------------------------------------------------------------------------
__global__ void v_transpose(const ushort_t* __restrict__ V, int vStride, int rowsPerBatch,
                            ushort_t* __restrict__ Vt, int Lk) {
    __shared__ __align__(16) ushort_t t[64][72];
    const int bh = blockIdx.y, k0 = blockIdx.x * 64;
    const int b = bh >> 4, h = bh & 15;
    const int tid = threadIdx.x;
    const ushort_t* src = V + (size_t)(b * rowsPerBatch + k0) * vStride + h * 64;
#pragma unroll
    for (int i = 0; i < 2; i++) {
        int ch = tid + i * 256;
        int r = ch >> 3, c = (ch & 7) * 8;
        *(short8*)(&t[r][c]) = *(const short8*)(src + (size_t)r * vStride + c);
    }
    __syncthreads();
#pragma unroll
    for (int i = 0; i < 2; i++) {
        int ch = tid + i * 256;
        int d = ch >> 3, c = (ch & 7) * 8;
        short8 o;
#pragma unroll
        for (int j = 0; j < 8; j++) o[j] = (short)t[c + j][d];
        *(short8*)(Vt + ((size_t)bh * 64 + d) * Lk + k0 + c) = o;
    }
}

// ---------------------------------------------------------------------------
// Elementwise f32 -> bf16 (vectorized x4)
// ---------------------------------------------------------------------------
__global__ void f32_to_bf16_vec(const float* __restrict__ in, ushort_t* __restrict__ out, int n4) {
    int i = blockIdx.x * blockDim.x + threadIdx.x;
    if (i < n4) {
        float4 v = ((const float4*)in)[i];
        ushort4v o;
        o[0] = f2bf(v.x); o[1] = f2bf(v.y); o[2] = f2bf(v.z); o[3] = f2bf(v.w);
        ((ushort4v*)out)[i] = o;
    }
}

// ---------------------------------------------------------------------------
// LayerNorm over C=1024, f32 in -> bf16 out. One row per block (256 thr).
// ---------------------------------------------------------------------------
__global__ void ln_rows(const float* __restrict__ in, ushort_t* __restrict__ out) {
    __shared__ float s1[4], s2[4];
    const int row = blockIdx.x;
    const int tid = threadIdx.x;
    const float4 v = ((const float4*)(in + (size_t)row * 1024))[tid];
    float s  = v.x + v.y + v.z + v.w;
    float ss = v.x * v.x + v.y * v.y + v.z * v.z + v.w * v.w;
#pragma unroll
    for (int d = 32; d >= 1; d >>= 1) {
        s  += __shfl_down(s, d, 64);
        ss += __shfl_down(ss, d, 64);
    }
    if ((tid & 63) == 0) { s1[tid >> 6] = s; s2[tid >> 6] = ss; }
    __syncthreads();
    float sum = s1[0] + s1[1] + s1[2] + s1[3];
    float sqs = s2[0] + s2[1] + s2[2] + s2[3];
    float mu  = sum * (1.0f / 1024.0f);
    float var = sqs * (1.0f / 1024.0f) - mu * mu;
    float rs  = rsqrtf(var + 1e-6f);
    ushort4v o;
    o[0] = f2bf((v.x - mu) * rs);
    o[1] = f2bf((v.y - mu) * rs);
    o[2] = f2bf((v.z - mu) * rs);
    o[3] = f2bf((v.w - mu) * rs);
    ((ushort4v*)(out + (size_t)row * 1024))[tid] = o;
}

#define EPI_BF16 0
#define EPI_GELU 1
#define EPI_RES  2

// ---------------------------------------------------------------------------
// 128x128 bf16 MFMA GEMM (m97-structure) + XCD-aware block swizzle.
// ---------------------------------------------------------------------------
template <int EPI>
__global__ void gemm_bt(const ushort_t* __restrict__ A, const ushort_t* __restrict__ Bt,
                        const float* __restrict__ bias, const float* __restrict__ res,
                        void* __restrict__ outp, int M, int N, int K) {
    __shared__ __align__(16) ushort_t As[128 * 64];
    __shared__ __align__(16) ushort_t Bs[128 * 64];
    const int tid = threadIdx.x;
    const int lane = tid & 63, wave = tid >> 6;
    const int nwg = gridDim.x * gridDim.y;
    const int sid = xcd_swz(blockIdx.y * gridDim.x + blockIdx.x, nwg);
    const int m0 = (sid / gridDim.x) * 128, n0 = (sid % gridDim.x) * 128;
    const int wr = (wave >> 1) * 64, wc = (wave & 1) * 64;
    const int lr = lane & 15, lg = lane >> 4;

    f32x4 acc[4][4];
#pragma unroll
    for (int i = 0; i < 4; i++)
#pragma unroll
        for (int j = 0; j < 4; j++) acc[i][j] = f32x4{0.f, 0.f, 0.f, 0.f};

    for (int k0 = 0; k0 < K; k0 += 64) {
#pragma unroll
        for (int i = 0; i < 4; i++) {
            int ch = tid + i * 256;
            int r = ch >> 3;
            int kcs = (((ch & 7) ^ (r & 7))) * 8;
            gld16(A  + (size_t)(m0 + r) * K + k0 + kcs, As + ch * 8);
            gld16(Bt + (size_t)(n0 + r) * K + k0 + kcs, Bs + ch * 8);
        }
        __syncthreads();
#pragma unroll
        for (int ks = 0; ks < 2; ks++) {
            short8 af[4], bfr[4];
#pragma unroll
            for (int m = 0; m < 4; m++) {
                int r = wr + m * 16 + lr;
                int kc = ks * 4 + lg;
                af[m] = *(const short8*)(As + r * 64 + ((kc ^ (r & 7)) << 3));
            }
#pragma unroll
            for (int n = 0; n < 4; n++) {
                int r = wc + n * 16 + lr;
                int kc = ks * 4 + lg;
                bfr[n] = *(const short8*)(Bs + r * 64 + ((kc ^ (r & 7)) << 3));
            }
#pragma unroll
            for (int m = 0; m < 4; m++)
#pragma unroll
                for (int n = 0; n < 4; n++)
                    acc[m][n] = __builtin_amdgcn_mfma_f32_16x16x32_bf16(af[m], bfr[n], acc[m][n], 0, 0, 0);
        }
        __syncthreads();
    }

#pragma unroll
    for (int m = 0; m < 4; m++) {
        int rowb = m0 + wr + m * 16 + lg * 4;
#pragma unroll
        for (int n = 0; n < 4; n++) {
            int col = n0 + wc + n * 16 + lr;
            float bcol = bias[col];
            f32x4 v = acc[m][n];
#pragma unroll
            for (int q = 0; q < 4; q++) {
                float x = v[q] + bcol;
                if (EPI == EPI_GELU) {
                    float u = 0.7978845608028654f * (x + 0.044715f * x * x * x);
                    x = 0.5f * x * (1.0f + tanhf(u));
                }
                size_t off = (size_t)(rowb + q) * N + col;
                if (EPI == EPI_RES) ((float*)outp)[off] = x + res[off];
                else                ((ushort_t*)outp)[off] = f2bf(x);
            }
        }
    }
}

// ---------------------------------------------------------------------------
// Flash attention, 32x32x16 MFMA. Block = 128 q-rows x 1 head, 4 waves of
// 32 q-rows each. Swapped QK^T (lane owns one q-row: q = lane&31), softmax
// seeded into the MFMA accumulator (C-in = -mrun), exp2 domain (log2e folded
// into Q), P kept in-register (cvt_pk + shfl_xor(32) redistribution), K/V^T
// double-buffered via global_load_lds.
// ---------------------------------------------------------------------------
__global__ __launch_bounds__(256, 3)
void attn_fwd(const ushort_t* __restrict__ Q, int qStride,
              const ushort_t* __restrict__ Kp, int kvStride, int kvBatchRows,
              const ushort_t* __restrict__ Vt, int Lk,
              ushort_t* __restrict__ O) {
    __shared__ __align__(16) ushort_t Ks[2][64 * 64];
    __shared__ __align__(16) ushort_t Vts[2][64 * 64];
    const int tid = threadIdx.x, lane = tid & 63, wave = tid >> 6;
    const int ql = lane & 31;   // this lane's q-row within the wave tile
    const int hh = lane >> 5;   // k/d slot half (0/1)
    const int sid = xcd_swz(blockIdx.x, gridDim.x);
    const int qb = sid & 15, hd = (sid >> 4) & 15, b = sid >> 8;
    const int qRow0 = b * 2048 + qb * 128;
    const int kvRow0 = b * kvBatchRows;
    const int hc = hd * 64;
    const ushort_t* vt_base = Vt + (size_t)(b * 16 + hd) * 64 * Lk;

    // Q fragments: lane ql's row, d = 16*mi + 8*hh + j; prescaled 0.125*log2(e)
    short8 qf[4];
    {
        const ushort_t* qrow = Q + (size_t)(qRow0 + wave * 32 + ql) * qStride + hc + hh * 8;
        const float s = 0.125f * 1.44269504088896f;
#pragma unroll
        for (int mi = 0; mi < 4; mi++) {
            short8 r = *(const short8*)(qrow + mi * 16);
#pragma unroll
            for (int j = 0; j < 8; j++) qf[mi][j] = (short)f2bf(bf2f((ushort_t)r[j]) * s);
        }
    }

    f32x16 o0, o1;
#pragma unroll
    for (int r = 0; r < 16; r++) { o0[r] = 0.f; o1[r] = 0.f; }
    float mrun = 0.f, lrun = 0.f;

    const int nt = Lk >> 6;
    const int sw = ql & 7;   // LDS swizzle key for this lane's fragment rows

    auto stage = [&](int buf, int kt) {
#pragma unroll
        for (int i = 0; i < 2; i++) {
            int ch = tid + i * 256;
            int r = ch >> 3;
            int kcs = (((ch & 7) ^ (r & 7))) * 8;
            gld16(Kp + (size_t)(kvRow0 + kt + r) * kvStride + hc + kcs, Ks[buf] + ch * 8);
            gld16(vt_base + (size_t)r * Lk + kt + kcs, Vts[buf] + ch * 8);
        }
    };

    stage(0, 0);
    __syncthreads();
    int cur = 0;

    for (int t = 0; t < nt; ++t) {
        if (t + 1 < nt) stage(cur ^ 1, (t + 1) * 64);

        const ushort_t* Kc = Ks[cur];
        const ushort_t* Vc = Vts[cur];

        // S' - mrun = K·Q^T (C seeded with -mrun). Lane: q = ql,
        // k' = 32*kb + (reg&3) + 8*(reg>>2) + 4*hh.
        f32x16 s0, s1;
#pragma unroll
        for (int r = 0; r < 16; r++) { s0[r] = -mrun; s1[r] = -mrun; }
        __builtin_amdgcn_s_setprio(1);
#pragma unroll
        for (int mi = 0; mi < 4; mi++) {
            short8 a0 = *(const short8*)(Kc + ql * 64 + (((2 * mi + hh) ^ sw) << 3));
            short8 a1 = *(const short8*)(Kc + (32 + ql) * 64 + (((2 * mi + hh) ^ sw) << 3));
            s0 = __builtin_amdgcn_mfma_f32_32x32x16_bf16(a0, qf[mi], s0, 0, 0, 0);
            s1 = __builtin_amdgcn_mfma_f32_32x32x16_bf16(a1, qf[mi], s1, 0, 0, 0);
        }
        __builtin_amdgcn_s_setprio(0);

        // row max (relative to mrun): in-reg tree + one cross-half exchange
        float mx = fmaxf(s0[0], s0[1]);
#pragma unroll
        for (int r = 2; r < 16; r++) mx = fmaxf(mx, s0[r]);
#pragma unroll
        for (int r = 0; r < 16; r++) mx = fmaxf(mx, s1[r]);
        mx = fmaxf(mx, __shfl_xor(mx, 32, 64));

        // defer-max: rescale only when growth exceeds 8 (exp2 domain)
        if (!__all(mx <= 8.0f)) {
            float d = fmaxf(mx, 0.0f);
            float al = exp2f(-d);
#pragma unroll
            for (int r = 0; r < 16; r++) { o0[r] *= al; o1[r] *= al; }
            lrun *= al;
            mrun += d;
#pragma unroll
            for (int r = 0; r < 16; r++) { s0[r] -= d; s1[r] -= d; }
        }

        float rsum = 0.f;
#pragma unroll
        for (int r = 0; r < 16; r++) { s0[r] = exp2f(s0[r]); rsum += s0[r]; }
#pragma unroll
        for (int r = 0; r < 16; r++) { s1[r] = exp2f(s1[r]); rsum += s1[r]; }
        rsum += __shfl_xor(rsum, 32, 64);
        lrun += rsum;

        // pack P to bf16 words: W[kb][g*2+i] covers k-quad 8*kb + 2*g + hh
        unsigned W0[8], W1[8];
#pragma unroll
        for (int g = 0; g < 4; g++) {
            asm("v_cvt_pk_bf16_f32 %0, %1, %2" : "=v"(W0[g * 2 + 0]) : "v"(s0[4 * g + 0]), "v"(s0[4 * g + 1]));
            asm("v_cvt_pk_bf16_f32 %0, %1, %2" : "=v"(W0[g * 2 + 1]) : "v"(s0[4 * g + 2]), "v"(s0[4 * g + 3]));
            asm("v_cvt_pk_bf16_f32 %0, %1, %2" : "=v"(W1[g * 2 + 0]) : "v"(s1[4 * g + 0]), "v"(s1[4 * g + 1]));
            asm("v_cvt_pk_bf16_f32 %0, %1, %2" : "=v"(W1[g * 2 + 1]) : "v"(s1[4 * g + 2]), "v"(s1[4 * g + 3]));
        }

        // O^T += V^T · P, window w contracts k in [16w, 16w+16)
        __builtin_amdgcn_s_setprio(1);
#pragma unroll
        for (int w = 0; w < 4; w++) {
            const int p2 = (w & 1) * 2;
            union { unsigned u[4]; short8 s8; } pf;
#pragma unroll
            for (int i = 0; i < 2; i++) {
                unsigned A0 = (w >> 1) ? W1[p2 * 2 + i] : W0[p2 * 2 + i];
                unsigned A1 = (w >> 1) ? W1[(p2 + 1) * 2 + i] : W0[(p2 + 1) * 2 + i];
                unsigned own  = hh ? A1 : A0;
                unsigned send = hh ? A0 : A1;
                unsigned recv = __shfl_xor(send, 32, 64);
                pf.u[0 + i] = hh ? recv : own;
                pf.u[2 + i] = hh ? own : recv;
            }
            short8 v0 = *(const short8*)(Vc + ql * 64 + (((2 * w + hh) ^ sw) << 3));
            short8 v1 = *(const short8*)(Vc + (32 + ql) * 64 + (((2 * w + hh) ^ sw) << 3));
            o0 = __builtin_amdgcn_mfma_f32_32x32x16_bf16(v0, pf.s8, o0, 0, 0, 0);
            o1 = __builtin_amdgcn_mfma_f32_32x32x16_bf16(v1, pf.s8, o1, 0, 0, 0);
        }
        __builtin_amdgcn_s_setprio(0);
        __syncthreads();   // prefetched tile landed; all waves done with cur
        cur ^= 1;
    }

    // epilogue: O[q][d], d = 32*dt + 8*g + 4*hh + (reg&3); l is lane-local
    float linv = 1.0f / lrun;
    ushort_t* orow = O + (size_t)(qRow0 + wave * 32 + ql) * 1024 + hc + 4 * hh;
#pragma unroll
    for (int g = 0; g < 4; g++) {
        ushort4v ov;
#pragma unroll
        for (int j = 0; j < 4; j++) ov[j] = f2bf(o0[4 * g + j] * linv);
        *(ushort4v*)(orow + 8 * g) = ov;
#pragma unroll
        for (int j = 0; j < 4; j++) ov[j] = f2bf(o1[4 * g + j] * linv);
        *(ushort4v*)(orow + 32 + 8 * g) = ov;
    }
}

// ---------------------------------------------------------------------------
// Host-side orchestration
// ---------------------------------------------------------------------------
extern "C" void kernel_launch(void* const* d_in, const int* in_sizes, int n_in,
                              void* d_out, int out_size, void* d_ws, size_t ws_size,
                              hipStream_t stream) {
    const float* x     = (const float*)d_in[0];
    const float* ctx   = (const float*)d_in[1];
    const float* w_qkv = (const float*)d_in[2];
    const float* b_qkv = (const float*)d_in[3];
    const float* w_os  = (const float*)d_in[4];
    const float* b_os  = (const float*)d_in[5];
    const float* w_qc  = (const float*)d_in[6];
    const float* b_qc  = (const float*)d_in[7];
    const float* w_kvc = (const float*)d_in[8];
    const float* b_kvc = (const float*)d_in[9];
    const float* w_oc  = (const float*)d_in[10];
    const float* b_oc  = (const float*)d_in[11];
    const float* w_fc1 = (const float*)d_in[12];
    const float* b_fc1 = (const float*)d_in[13];
    const float* w_fc2 = (const float*)d_in[14];
    const float* b_fc2 = (const float*)d_in[15];
    float* out = (float*)d_out;

    char* ws = (char*)d_ws;
    // weight arena (bf16, transposed N x K)
    ushort_t* wqkvT = (ushort_t*)(ws + 0);          // 3072x1024
    ushort_t* wosT  = (ushort_t*)(ws + 6291456);    // 1024x1024
    ushort_t* wqcT  = (ushort_t*)(ws + 8388608);    // 1024x1024
    ushort_t* wkvcT = (ushort_t*)(ws + 10485760);   // 2048x1024
    ushort_t* wocT  = (ushort_t*)(ws + 14680064);   // 1024x1024
    ushort_t* wfc1T = (ushort_t*)(ws + 16777216);   // 4096x1024
    ushort_t* wfc2T = (ushort_t*)(ws + 25165824);   // 1024x4096
    // activation arena (liveness-overlapped)
    ushort_t* qkv_bf  = (ushort_t*)(ws + 33554432); // 8192x3072 (self phase)
    ushort_t* q_bf    = (ushort_t*)(ws + 33554432); // 8192x1024 (cross phase)
    ushort_t* kv_bf   = (ushort_t*)(ws + 50331648); // 4096x2048 (cross phase)
    ushort_t* vt_c    = (ushort_t*)(ws + 67108864); // 64*64x1024 cross V^T (cross phase)
    ushort_t* ffn_bf  = (ushort_t*)(ws + 33554432); // 8192x4096 (ffn phase)
    ushort_t* ctx_bf  = (ushort_t*)(ws + 83886080); // 4096x1024 (dead before ffn)
    ushort_t* attn_bf = (ushort_t*)(ws + 92274688); // 8192x1024 (dead before ffn)
    ushort_t* h_bf    = (ushort_t*)(ws + 109051904);// 8192x1024 (LN out; dead during attn)
    ushort_t* vt_s    = (ushort_t*)(ws + 109051904);// 64*64x2048 self V^T (aliases h_bf)

    const dim3 tb(256);
    // weight conversion/transpose
    w_transpose_bf16<<<dim3(48, 16), tb, 0, stream>>>(w_qkv, wqkvT, 1024, 3072);
    w_transpose_bf16<<<dim3(16, 16), tb, 0, stream>>>(w_os,  wosT,  1024, 1024);
    w_transpose_bf16<<<dim3(16, 16), tb, 0, stream>>>(w_qc,  wqcT,  1024, 1024);
    w_transpose_bf16<<<dim3(32, 16), tb, 0, stream>>>(w_kvc, wkvcT, 1024, 2048);
    w_transpose_bf16<<<dim3(16, 16), tb, 0, stream>>>(w_oc,  wocT,  1024, 1024);
    w_transpose_bf16<<<dim3(64, 16), tb, 0, stream>>>(w_fc1, wfc1T, 1024, 4096);
    w_transpose_bf16<<<dim3(16, 64), tb, 0, stream>>>(w_fc2, wfc2T, 4096, 1024);
    f32_to_bf16_vec<<<4096, tb, 0, stream>>>(ctx, ctx_bf, 1048576);

    // ---- self-attention sub-block ----
    ln_rows<<<8192, tb, 0, stream>>>(x, h_bf);
    gemm_bt<EPI_BF16><<<dim3(24, 64), tb, 0, stream>>>(h_bf, wqkvT, b_qkv, nullptr, qkv_bf, 8192, 3072, 1024);
    v_transpose<<<dim3(32, 64), tb, 0, stream>>>(qkv_bf + 2048, 3072, 2048, vt_s, 2048);
    attn_fwd<<<dim3(1024), tb, 0, stream>>>(qkv_bf, 3072, qkv_bf + 1024, 3072, 2048,
                                            vt_s, 2048, attn_bf);
    gemm_bt<EPI_RES><<<dim3(8, 64), tb, 0, stream>>>(attn_bf, wosT, b_os, x, out, 8192, 1024, 1024);

    // ---- cross-attention sub-block ----
    ln_rows<<<8192, tb, 0, stream>>>(out, h_bf);
    gemm_bt<EPI_BF16><<<dim3(8, 64), tb, 0, stream>>>(h_bf, wqcT, b_qc, nullptr, q_bf, 8192, 1024, 1024);
    gemm_bt<EPI_BF16><<<dim3(16, 32), tb, 0, stream>>>(ctx_bf, wkvcT, b_kvc, nullptr, kv_bf, 4096, 2048, 1024);
    v_transpose<<<dim3(16, 64), tb, 0, stream>>>(kv_bf + 1024, 2048, 1024, vt_c, 1024);
    attn_fwd<<<dim3(1024), tb, 0, stream>>>(q_bf, 1024, kv_bf, 2048, 1024,
                                            vt_c, 1024, attn_bf);
    gemm_bt<EPI_RES><<<dim3(8, 64), tb, 0, stream>>>(attn_bf, wocT, b_oc, out, out, 8192, 1024, 1024);

    // ---- FFN sub-block ----
    ln_rows<<<8192, tb, 0, stream>>>(out, h_bf);
    gemm_bt<EPI_GELU><<<dim3(32, 64), tb, 0, stream>>>(h_bf, wfc1T, b_fc1, nullptr, ffn_bf, 8192, 4096, 1024);
    gemm_bt<EPI_RES><<<dim3(8, 64), tb, 0, stream>>>(ffn_bf, wfc2T, b_fc2, out, out, 8192, 1024, 4096);
}